// Round 1
// baseline (861.900 us; speedup 1.0000x reference)
//
#include <hip/hip_runtime.h>

// Problem constants
#define BATCH 4096
#define NI 1024
#define HID 2048
#define TSTEPS 20
#define NA 45

typedef __bf16 bf16x8 __attribute__((ext_vector_type(8)));
typedef float floatx4 __attribute__((ext_vector_type(4)));

struct StepMeta {
    float ac0, ac1, delta, chosen;
    int pack, dac, alive, pad;
};

__device__ __forceinline__ unsigned short f2bf(float x) {
    union { float f; unsigned int u; } un; un.f = x;
    unsigned int r = un.u + 0x7FFFu + ((un.u >> 16) & 1u);
    return (unsigned short)(r >> 16);
}

// ---------------------------------------------------------------------------
// Kernel 1: per-batch-element 20-step state machine (exact fp32 replication)
// ---------------------------------------------------------------------------
__global__ void scan_kernel(const float* __restrict__ camera,
                            const int* __restrict__ fb_in, const int* __restrict__ lr_in,
                            const int* __restrict__ jp_in, const int* __restrict__ ss_in,
                            const int* __restrict__ at_in, StepMeta* __restrict__ meta) {
    int b = blockIdx.x * 256 + threadIdx.x;
    if (b >= BATCH) return;
    float cam0 = camera[2 * b], cam1 = camera[2 * b + 1];
    int afb = fb_in[b], alr = lr_in[b], ajp = jp_in[b], ass = ss_in[b], aat = at_in[b];
    float ac0 = 0.f, ac1 = 0.f, delta = 0.0625f;  // MIN_DELTA = 0.5/8
    int rfb = 0, rlr = 0, rjp = 0, rss = 0, rat = 0;
    bool chosen = false, commited = false;
    int cam_steps = 0;
    bool camzero = (fabsf(cam0) < 1e-5f) && (fabsf(cam1) < 1e-5f);
    for (int t = 0; t < TSTEPS; t++) {
        StepMeta m;
        m.ac0 = ac0; m.ac1 = ac1; m.delta = delta; m.chosen = chosen ? 1.f : 0.f;
        m.pack = rfb | (rlr << 4) | (rjp << 8) | (rss << 12) | (rat << 16);
        m.alive = commited ? 0 : 1;
        bool commit = (camzero || cam_steps >= 6) &&
                      rfb == afb && rlr == alr && rjp == ajp && rss == ass && rat == aat;
        int dac = 0; bool modified = commit;
        if (!modified && rfb != afb) { dac = (afb == 0 ? rfb - 1 + 6  : afb - 1 + 6 ); rfb = afb; modified = true; }
        if (!modified && rlr != alr) { dac = (alr == 0 ? rlr - 1 + 8  : alr - 1 + 8 ); rlr = alr; modified = true; }
        if (!modified && rjp != ajp) { dac = (ajp == 0 ? rjp - 1 + 10 : ajp - 1 + 10); rjp = ajp; modified = true; }
        if (!modified && rss != ass) { dac = (ass == 0 ? rss - 1 + 11 : ass - 1 + 11); rss = ass; modified = true; }
        if (!modified && rat != aat) { dac = (aat == 0 ? rat - 1 + 14 : aat - 1 + 14); rat = aat; modified = true; }
        // NOTE: reference compares BOTH cam0 and cam1 against ac0 (replicated as-is)
        if (!modified && !chosen &&
            (fabsf(cam0 - ac0) > delta * 2.f || fabsf(cam1 - ac0) > delta * 2.f)) {
            dac = 5; delta = fminf(delta * 2.f, 0.5f); modified = true;
        }
        if (!modified) {
            bool incX = cam0 >= ac0, incY = cam1 >= ac1;
            dac = 1 + (incX ? 1 : 0) + (incY ? 2 : 0);
            ac0 += incX ? delta : -delta;
            ac1 += incY ? delta : -delta;
            delta *= 0.5f;
            chosen = true;
            cam_steps++;
        }
        commited = commited || commit;
        m.dac = dac; m.pad = 0;
        meta[b * TSTEPS + t] = m;
    }
}

// ---------------------------------------------------------------------------
// Kernel 2: fc_input fp32 -> bf16 (elementwise, vectorized)
// ---------------------------------------------------------------------------
__global__ void convert_fc(const float* __restrict__ fc, unsigned short* __restrict__ Ab) {
    int idx = blockIdx.x * 256 + threadIdx.x;  // covers BATCH*NI/4
    float4 v = ((const float4*)fc)[idx];
    ushort4 o;
    o.x = f2bf(v.x); o.y = f2bf(v.y); o.z = f2bf(v.z); o.w = f2bf(v.w);
    ((ushort4*)Ab)[idx] = o;
}

// ---------------------------------------------------------------------------
// Kernel 3: W1[0:1024][2048] fp32 -> bf16, transposed to Wt[2048][1024]
// ---------------------------------------------------------------------------
__global__ void transpose_w1(const float* __restrict__ W1, unsigned short* __restrict__ Wt) {
    __shared__ float tile[32][33];
    int k0 = blockIdx.x * 32, n0 = blockIdx.y * 32;
    int tx = threadIdx.x, ty = threadIdx.y;  // (32, 8)
    for (int i = 0; i < 4; i++)
        tile[ty + 8 * i][tx] = W1[(size_t)(k0 + ty + 8 * i) * HID + n0 + tx];
    __syncthreads();
    for (int i = 0; i < 4; i++) {
        int n = ty + 8 * i;
        Wt[(size_t)(n0 + n) * NI + k0 + tx] = f2bf(tile[tx][n]);
    }
}

// ---------------------------------------------------------------------------
// Kernel 4: base[4096][2048] = A[4096][1024](bf16) @ B[1024][2048](bf16, given
// transposed as Wt[n][k]).  128x128 block tile, 4 waves, 64x64 per wave,
// 16x16x32 bf16 MFMA. Verified layouts: A-frag A[m=lane&15][k=q*8+j],
// B-frag B[k=q*8+j][n=lane&15], C/D col=lane&15 row=q*4+reg.
// ---------------------------------------------------------------------------
__global__ __launch_bounds__(256) void gemm_base(const unsigned short* __restrict__ Ab,
                                                 const unsigned short* __restrict__ Wt,
                                                 float* __restrict__ C) {
    __shared__ __align__(16) unsigned short At[128 * 40];  // pad 32->40: 2-way max
    __shared__ __align__(16) unsigned short Bt[128 * 40];
    int bn = blockIdx.x, bm = blockIdx.y;
    int m0 = bm * 128, n0 = bn * 128;
    int tid = threadIdx.x;
    int wave = tid >> 6, lane = tid & 63;
    int wr = wave >> 1, wc = wave & 1;
    int l15 = lane & 15, q = lane >> 4;
    floatx4 acc[4][4];
    for (int a = 0; a < 4; a++) for (int c = 0; c < 4; c++) acc[a][c] = (floatx4){0.f, 0.f, 0.f, 0.f};
    int lr = tid >> 1;            // staging row 0..127
    int lc = (tid & 1) * 16;      // staging col 0 or 16
    for (int k0 = 0; k0 < NI; k0 += 32) {
        __syncthreads();
        float4 a0  = *(const float4*)&Ab[(size_t)(m0 + lr) * NI + k0 + lc];
        float4 a1  = *(const float4*)&Ab[(size_t)(m0 + lr) * NI + k0 + lc + 8];
        float4 bb0 = *(const float4*)&Wt[(size_t)(n0 + lr) * NI + k0 + lc];
        float4 bb1 = *(const float4*)&Wt[(size_t)(n0 + lr) * NI + k0 + lc + 8];
        *(float4*)&At[lr * 40 + lc]     = a0;
        *(float4*)&At[lr * 40 + lc + 8] = a1;
        *(float4*)&Bt[lr * 40 + lc]     = bb0;
        *(float4*)&Bt[lr * 40 + lc + 8] = bb1;
        __syncthreads();
        bf16x8 af[4], bf[4];
        for (int mr = 0; mr < 4; mr++)
            af[mr] = *(const bf16x8*)&At[(wr * 64 + mr * 16 + l15) * 40 + q * 8];
        for (int nc = 0; nc < 4; nc++)
            bf[nc] = *(const bf16x8*)&Bt[(wc * 64 + nc * 16 + l15) * 40 + q * 8];
        for (int mr = 0; mr < 4; mr++)
            for (int nc = 0; nc < 4; nc++)
                acc[mr][nc] = __builtin_amdgcn_mfma_f32_16x16x32_bf16(af[mr], bf[nc], acc[mr][nc], 0, 0, 0);
    }
    for (int mr = 0; mr < 4; mr++)
        for (int nc = 0; nc < 4; nc++)
            for (int r = 0; r < 4; r++) {
                int row = m0 + wr * 64 + mr * 16 + q * 4 + r;
                int col = n0 + wc * 64 + nc * 16 + l15;
                C[(size_t)row * HID + col] = acc[mr][nc][r];
            }
}

// ---------------------------------------------------------------------------
// Kernel 5: fused per-b MLP + CE.  One block per b (256 threads).
// h[t][j] = base[b][j]+b1[j] + ac/delta/chosen FMAs + 5 one-hot row gathers;
// S = silu(h) staged per 256-wide j tile; phase B: register-blocked fp32 GEMM
// logits(20x48) += S(20x256) @ W2tile(256x48); then log-softmax CE.
// ---------------------------------------------------------------------------
__global__ __launch_bounds__(256) void fused_mlp(const float* __restrict__ base,
                                                 const float* __restrict__ W1,
                                                 const float* __restrict__ b1,
                                                 const float* __restrict__ W2,
                                                 const float* __restrict__ b2,
                                                 const StepMeta* __restrict__ meta,
                                                 float* __restrict__ loss_out) {
    __shared__ __align__(16) float S[TSTEPS * 260];    // pad 256->260: conflict-free
    __shared__ __align__(16) float W2T[256 * 48];      // [jj][k], k padded 45->48
    __shared__ __align__(16) float logitsL[TSTEPS * 48];
    __shared__ StepMeta sm[TSTEPS];
    __shared__ float ceArr[TSTEPS], aliveArr[TSTEPS];

    int b = blockIdx.x;
    int tid = threadIdx.x;
    if (tid < TSTEPS) sm[tid] = meta[b * TSTEPS + tid];
    __syncthreads();

    bool actT = tid < 240;
    int t_own = tid / 12, kb = tid % 12;   // thread owns (t_own, k = kb*4..kb*4+3)
    floatx4 acc = (floatx4){0.f, 0.f, 0.f, 0.f};

    for (int jt = 0; jt < 8; jt++) {
        int j0 = jt * 256;
        if (jt) __syncthreads();  // previous phase-B readers done before overwrite
        // stage W2 tile (global [j][45] -> LDS [jj][48])
        for (int i = 0; i < 45; i++) {
            int idx = tid + i * 256;          // 0..11519
            int jj = idx / 45, k = idx - jj * 45;
            W2T[jj * 48 + k] = W2[(size_t)(j0 + jj) * NA + k];
        }
        // phase A: h assembly + silu for this thread's j
        int j = j0 + tid;
        float hbase = base[(size_t)b * HID + j] + b1[j];
        const float* Wx = W1 + (size_t)NI * HID + j;   // extra rows, stride HID
        float w_ac0 = Wx[0];
        float w_ac1 = Wx[HID];
        float w_del = Wx[46 * HID];
        float w_cho = Wx[47 * HID];
        for (int t = 0; t < TSTEPS; t++) {
            StepMeta m = sm[t];
            int fb = m.pack & 15, lr = (m.pack >> 4) & 15, jp = (m.pack >> 8) & 15;
            int ss = (m.pack >> 12) & 15, at = (m.pack >> 16) & 255;
            float h = hbase + m.ac0 * w_ac0 + m.ac1 * w_ac1 + m.delta * w_del + m.chosen * w_cho
                    + Wx[(2 + fb) * HID] + Wx[(5 + lr) * HID] + Wx[(8 + jp) * HID]
                    + Wx[(10 + ss) * HID] + Wx[(14 + at) * HID];
            float e = __expf(-h);
            S[t * 260 + tid] = h * __builtin_amdgcn_rcpf(1.0f + e);
        }
        __syncthreads();
        // phase B: acc[k] += sum_jj S[t][jj] * W2T[jj][k], 4x4 register blocked
        if (actT) {
            const float* Sp = &S[t_own * 260];
            for (int jjb = 0; jjb < 64; jjb++) {
                float4 s4 = *(const float4*)&Sp[jjb * 4];
                const float* wb = &W2T[(jjb * 4) * 48 + kb * 4];
                float4 w0 = *(const float4*)&wb[0];
                float4 w1 = *(const float4*)&wb[48];
                float4 w2 = *(const float4*)&wb[96];
                float4 w3 = *(const float4*)&wb[144];
                acc.x += s4.x * w0.x + s4.y * w1.x + s4.z * w2.x + s4.w * w3.x;
                acc.y += s4.x * w0.y + s4.y * w1.y + s4.z * w2.y + s4.w * w3.y;
                acc.z += s4.x * w0.z + s4.y * w1.z + s4.z * w2.z + s4.w * w3.z;
                acc.w += s4.x * w0.w + s4.y * w1.w + s4.z * w2.w + s4.w * w3.w;
            }
        }
    }
    if (actT) *(floatx4*)&logitsL[t_own * 48 + kb * 4] = acc;
    __syncthreads();
    // CE per t (threads 0..19), two-pass to keep VGPRs low
    if (tid < TSTEPS) {
        int t = tid;
        float mx = -1e30f;
        for (int k = 0; k < NA; k++) mx = fmaxf(mx, logitsL[t * 48 + k] + b2[k]);
        float sum = 0.f;
        for (int k = 0; k < NA; k++) sum += __expf(logitsL[t * 48 + k] + b2[k] - mx);
        int dac = sm[t].dac;
        float ld = logitsL[t * 48 + dac] + b2[dac];
        float ce = -(ld - mx - logf(sum));
        ceArr[t] = sm[t].alive ? ce : 0.f;
        aliveArr[t] = (float)sm[t].alive;
    }
    __syncthreads();
    if (tid == 0) {
        float s = 0.f, a = 0.f;
        for (int t = 0; t < TSTEPS; t++) { s += ceArr[t]; a += aliveArr[t]; }
        loss_out[b] = s / a;
    }
}

// ---------------------------------------------------------------------------
// Kernel 6: deterministic final reduction over 4096 per-b losses
// ---------------------------------------------------------------------------
__global__ void reduce_loss(const float* __restrict__ loss, float* __restrict__ out) {
    int tid = threadIdx.x;  // 256
    float s = 0.f;
    for (int i = tid; i < BATCH; i += 256) s += loss[i];
    for (int off = 32; off > 0; off >>= 1) s += __shfl_down(s, off, 64);
    __shared__ float wsum[4];
    if ((tid & 63) == 0) wsum[tid >> 6] = s;
    __syncthreads();
    if (tid == 0) out[0] = (wsum[0] + wsum[1] + wsum[2] + wsum[3]) * (1.0f / (float)BATCH);
}

// ---------------------------------------------------------------------------
extern "C" void kernel_launch(void* const* d_in, const int* in_sizes, int n_in,
                              void* d_out, int out_size, void* d_ws, size_t ws_size,
                              hipStream_t stream) {
    const float* fc_input = (const float*)d_in[0];
    const float* camera   = (const float*)d_in[1];
    const int*   fb       = (const int*)d_in[2];
    const int*   lr       = (const int*)d_in[3];
    const int*   jp       = (const int*)d_in[4];
    const int*   ss       = (const int*)d_in[5];
    const int*   at       = (const int*)d_in[6];
    const float* W1       = (const float*)d_in[7];
    const float* b1       = (const float*)d_in[8];
    const float* W2       = (const float*)d_in[9];
    const float* b2       = (const float*)d_in[10];
    float* out = (float*)d_out;

    char* ws = (char*)d_ws;
    unsigned short* Ab   = (unsigned short*)(ws);                       //  8,388,608 B
    unsigned short* Wt   = (unsigned short*)(ws + 8388608);             //  4,194,304 B
    float*          baseB= (float*)(ws + 12582912);                     // 33,554,432 B
    StepMeta*       meta = (StepMeta*)(ws + 46137344);                  //  2,621,440 B
    float*          lossB= (float*)(ws + 48758784);                     //     16,384 B

    scan_kernel<<<BATCH / 256, 256, 0, stream>>>(camera, fb, lr, jp, ss, at, meta);
    convert_fc<<<(BATCH * NI / 4) / 256, 256, 0, stream>>>(fc_input, Ab);
    transpose_w1<<<dim3(NI / 32, HID / 32), dim3(32, 8), 0, stream>>>(W1, Wt);
    gemm_base<<<dim3(HID / 128, BATCH / 128), 256, 0, stream>>>(Ab, Wt, baseB);
    fused_mlp<<<BATCH, 256, 0, stream>>>(baseB, W1, b1, W2, b2, meta, lossB);
    reduce_loss<<<1, 256, 0, stream>>>(lossB, out);
}

// Round 2
// 325.017 us; speedup vs baseline: 2.6519x; 2.6519x over previous
//
#include <hip/hip_runtime.h>

// Problem constants
#define BATCH 4096
#define NI 1024
#define HID 2048
#define TSTEPS 20
#define NA 45
#define SS 264   // fused S row stride in bf16 elems (256 + 8 pad)

typedef __bf16 bf16x8 __attribute__((ext_vector_type(8)));
typedef float floatx4 __attribute__((ext_vector_type(4)));

struct StepMeta {
    float ac0, ac1, delta, chosen;
    int chg;    // (oldCol<<8)|newCol applied entering this step, or -1
    int dac, alive, pad;
};

__device__ __forceinline__ unsigned short f2bf(float x) {
    union { float f; unsigned int u; } un; un.f = x;
    unsigned int r = un.u + 0x7FFFu + ((un.u >> 16) & 1u);
    return (unsigned short)(r >> 16);
}

// ---------------------------------------------------------------------------
// Kernel 1: per-batch-element 20-step state machine (exact fp32 replication).
// Emits per-step absolute state + the one-hot column swap (chg) applied since
// the previous step (at most ONE discrete change per step by construction).
// x-column offsets of the extras block: ac0=0 ac1=1 fb=2..4 lr=5..7 jp=8..9
// ss=10..13 at=14..45 delta=46 chosen=47.
// ---------------------------------------------------------------------------
__global__ void scan_kernel(const float* __restrict__ camera,
                            const int* __restrict__ fb_in, const int* __restrict__ lr_in,
                            const int* __restrict__ jp_in, const int* __restrict__ ss_in,
                            const int* __restrict__ at_in, StepMeta* __restrict__ meta) {
    int b = blockIdx.x * 256 + threadIdx.x;
    if (b >= BATCH) return;
    float cam0 = camera[2 * b], cam1 = camera[2 * b + 1];
    int afb = fb_in[b], alr = lr_in[b], ajp = jp_in[b], ass = ss_in[b], aat = at_in[b];
    float ac0 = 0.f, ac1 = 0.f, delta = 0.0625f;  // MIN_DELTA = 0.5/8
    int rfb = 0, rlr = 0, rjp = 0, rss = 0, rat = 0;
    bool chosen = false, commited = false;
    int cam_steps = 0;
    int chgPending = -1;
    bool camzero = (fabsf(cam0) < 1e-5f) && (fabsf(cam1) < 1e-5f);
    for (int t = 0; t < TSTEPS; t++) {
        StepMeta m;
        m.ac0 = ac0; m.ac1 = ac1; m.delta = delta; m.chosen = chosen ? 1.f : 0.f;
        m.chg = chgPending; chgPending = -1;
        m.alive = commited ? 0 : 1;
        bool commit = (camzero || cam_steps >= 6) &&
                      rfb == afb && rlr == alr && rjp == ajp && rss == ass && rat == aat;
        int dac = 0; bool modified = commit;
        if (!modified && rfb != afb) { dac = (afb == 0 ? rfb - 1 + 6  : afb - 1 + 6 ); chgPending = ((2  + rfb) << 8) | (2  + afb); rfb = afb; modified = true; }
        if (!modified && rlr != alr) { dac = (alr == 0 ? rlr - 1 + 8  : alr - 1 + 8 ); chgPending = ((5  + rlr) << 8) | (5  + alr); rlr = alr; modified = true; }
        if (!modified && rjp != ajp) { dac = (ajp == 0 ? rjp - 1 + 10 : ajp - 1 + 10); chgPending = ((8  + rjp) << 8) | (8  + ajp); rjp = ajp; modified = true; }
        if (!modified && rss != ass) { dac = (ass == 0 ? rss - 1 + 11 : ass - 1 + 11); chgPending = ((10 + rss) << 8) | (10 + ass); rss = ass; modified = true; }
        if (!modified && rat != aat) { dac = (aat == 0 ? rat - 1 + 14 : aat - 1 + 14); chgPending = ((14 + rat) << 8) | (14 + aat); rat = aat; modified = true; }
        // NOTE: reference compares BOTH cam0 and cam1 against ac0 (replicated as-is)
        if (!modified && !chosen &&
            (fabsf(cam0 - ac0) > delta * 2.f || fabsf(cam1 - ac0) > delta * 2.f)) {
            dac = 5; delta = fminf(delta * 2.f, 0.5f); modified = true;
        }
        if (!modified) {
            bool incX = cam0 >= ac0, incY = cam1 >= ac1;
            dac = 1 + (incX ? 1 : 0) + (incY ? 2 : 0);
            ac0 += incX ? delta : -delta;
            ac1 += incY ? delta : -delta;
            delta *= 0.5f;
            chosen = true;
            cam_steps++;
        }
        commited = commited || commit;
        m.dac = dac; m.pad = 0;
        meta[b * TSTEPS + t] = m;
    }
}

// ---------------------------------------------------------------------------
// Kernel 2: fc_input fp32 -> bf16 (elementwise, vectorized)
// ---------------------------------------------------------------------------
__global__ void convert_fc(const float* __restrict__ fc, unsigned short* __restrict__ Ab) {
    int idx = blockIdx.x * 256 + threadIdx.x;  // covers BATCH*NI/4
    float4 v = ((const float4*)fc)[idx];
    ushort4 o;
    o.x = f2bf(v.x); o.y = f2bf(v.y); o.z = f2bf(v.z); o.w = f2bf(v.w);
    ((ushort4*)Ab)[idx] = o;
}

// ---------------------------------------------------------------------------
// Kernel 3: W1[0:1024][2048] fp32 -> bf16, transposed to Wt[2048][1024]
// ---------------------------------------------------------------------------
__global__ void transpose_w1(const float* __restrict__ W1, unsigned short* __restrict__ Wt) {
    __shared__ float tile[32][33];
    int k0 = blockIdx.x * 32, n0 = blockIdx.y * 32;
    int tx = threadIdx.x, ty = threadIdx.y;  // (32, 8)
    for (int i = 0; i < 4; i++)
        tile[ty + 8 * i][tx] = W1[(size_t)(k0 + ty + 8 * i) * HID + n0 + tx];
    __syncthreads();
    for (int i = 0; i < 4; i++) {
        int n = ty + 8 * i;
        Wt[(size_t)(n0 + n) * NI + k0 + tx] = f2bf(tile[tx][n]);
    }
}

// ---------------------------------------------------------------------------
// Kernel 3b: W2[2048][45] fp32 -> bf16 transposed W2T[48][2048], rows 45..47
// zero-padded (MFMA N-tile padding).
// ---------------------------------------------------------------------------
__global__ void convert_w2(const float* __restrict__ W2, unsigned short* __restrict__ W2T) {
    int k = blockIdx.x * 256 + threadIdx.x;  // 0..2047
    for (int n = 0; n < 48; n++)
        W2T[(size_t)n * HID + k] = (n < NA) ? f2bf(W2[(size_t)k * NA + n]) : (unsigned short)0;
}

// ---------------------------------------------------------------------------
// Kernel 4: base[4096][2048] = A @ W1[:1024] (bf16 MFMA) with the t=0-constant
// epilogue folded in: + b1 + initial one-hot rows (2,5,8,10,14) + 0.0625*w_delta.
// ---------------------------------------------------------------------------
__global__ __launch_bounds__(256) void gemm_base(const unsigned short* __restrict__ Ab,
                                                 const unsigned short* __restrict__ Wt,
                                                 const float* __restrict__ W1,
                                                 const float* __restrict__ b1,
                                                 float* __restrict__ C) {
    __shared__ __align__(16) unsigned short At[128 * 40];
    __shared__ __align__(16) unsigned short Bt[128 * 40];
    int bn = blockIdx.x, bm = blockIdx.y;
    int m0 = bm * 128, n0 = bn * 128;
    int tid = threadIdx.x;
    int wave = tid >> 6, lane = tid & 63;
    int wr = wave >> 1, wc = wave & 1;
    int l15 = lane & 15, q = lane >> 4;
    floatx4 acc[4][4];
    for (int a = 0; a < 4; a++) for (int c = 0; c < 4; c++) acc[a][c] = (floatx4){0.f, 0.f, 0.f, 0.f};
    int lr = tid >> 1;
    int lc = (tid & 1) * 16;
    for (int k0 = 0; k0 < NI; k0 += 32) {
        __syncthreads();
        float4 a0  = *(const float4*)&Ab[(size_t)(m0 + lr) * NI + k0 + lc];
        float4 a1  = *(const float4*)&Ab[(size_t)(m0 + lr) * NI + k0 + lc + 8];
        float4 bb0 = *(const float4*)&Wt[(size_t)(n0 + lr) * NI + k0 + lc];
        float4 bb1 = *(const float4*)&Wt[(size_t)(n0 + lr) * NI + k0 + lc + 8];
        *(float4*)&At[lr * 40 + lc]     = a0;
        *(float4*)&At[lr * 40 + lc + 8] = a1;
        *(float4*)&Bt[lr * 40 + lc]     = bb0;
        *(float4*)&Bt[lr * 40 + lc + 8] = bb1;
        __syncthreads();
        bf16x8 af[4], bf[4];
        for (int mr = 0; mr < 4; mr++)
            af[mr] = *(const bf16x8*)&At[(wr * 64 + mr * 16 + l15) * 40 + q * 8];
        for (int nc = 0; nc < 4; nc++)
            bf[nc] = *(const bf16x8*)&Bt[(wc * 64 + nc * 16 + l15) * 40 + q * 8];
        for (int mr = 0; mr < 4; mr++)
            for (int nc = 0; nc < 4; nc++)
                acc[mr][nc] = __builtin_amdgcn_mfma_f32_16x16x32_bf16(af[mr], bf[nc], acc[mr][nc], 0, 0, 0);
    }
    for (int nc = 0; nc < 4; nc++) {
        int col = n0 + wc * 64 + nc * 16 + l15;
        const float* We = W1 + (size_t)NI * HID + col;
        float cv = b1[col] + We[2 * HID] + We[5 * HID] + We[8 * HID] + We[10 * HID]
                 + We[14 * HID] + 0.0625f * We[46 * HID];
        for (int mr = 0; mr < 4; mr++)
            for (int r = 0; r < 4; r++) {
                int row = m0 + wr * 64 + mr * 16 + q * 4 + r;
                C[(size_t)row * HID + col] = acc[mr][nc][r] + cv;
            }
    }
}

// ---------------------------------------------------------------------------
// Kernel 5: fused per-b MLP + CE. One block per b, 256 threads.
// Phase A (incremental): h[t] = h[t-1] + delta-FMAs + (row_new - row_old);
// silu -> bf16 S tile (20x256) in LDS. Phase B: MFMA logits += S @ W2T-frags
// (K split 64/wave, fp32 accum across all 8 j-tiles), cross-wave reduce, CE.
// ---------------------------------------------------------------------------
__global__ __launch_bounds__(256) void fused_mlp(const float* __restrict__ base,
                                                 const float* __restrict__ W1,
                                                 const unsigned short* __restrict__ W2T,
                                                 const float* __restrict__ b2,
                                                 const StepMeta* __restrict__ meta,
                                                 float* __restrict__ loss_out) {
    __shared__ __align__(16) __bf16 S[32 * SS];          // 16896 B, rows 20..31 stay 0
    __shared__ __align__(16) float logitsP[4 * TSTEPS * 48];  // per-wave partials
    __shared__ __align__(16) float logitsF[TSTEPS * 48];
    __shared__ float d0s[TSTEPS], d1s[TSTEPS], dds[TSTEPS], dchs[TSTEPS];
    __shared__ int chgs[TSTEPS], dacsS[TSTEPS], alivesS[TSTEPS];
    __shared__ float ceArr[TSTEPS], afArr[TSTEPS];

    int b = blockIdx.x, tid = threadIdx.x;
    int wave = tid >> 6, lane = tid & 63, l15 = lane & 15, q = lane >> 4;

    for (int i = tid; i < 32 * SS * 2 / 16; i += 256) ((uint4*)S)[i] = make_uint4(0, 0, 0, 0);
    if (tid < TSTEPS) {
        StepMeta m = meta[b * TSTEPS + tid];
        dacsS[tid] = m.dac; alivesS[tid] = m.alive; chgs[tid] = m.chg;
        if (tid == 0) { d0s[0] = 0.f; d1s[0] = 0.f; dds[0] = 0.f; dchs[0] = 0.f; }
        else {
            StepMeta p = meta[b * TSTEPS + tid - 1];
            d0s[tid] = m.ac0 - p.ac0; d1s[tid] = m.ac1 - p.ac1;
            dds[tid] = m.delta - p.delta; dchs[tid] = m.chosen - p.chosen;
        }
    }
    __syncthreads();

    const float* Wx = W1 + (size_t)NI * HID;
    floatx4 acc[2][3];
    for (int a = 0; a < 2; a++) for (int c = 0; c < 3; c++) acc[a][c] = (floatx4){0.f, 0.f, 0.f, 0.f};

    for (int jt = 0; jt < 8; jt++) {
        if (jt) __syncthreads();                // phase-B readers of prev tile done
        int j = jt * 256 + tid;
        float w0 = Wx[j], w1 = Wx[HID + j];
        float wdl = Wx[46 * HID + j], wch = Wx[47 * HID + j];
        float h = base[(size_t)b * HID + j];    // includes b1 + t=0 constants
        for (int t = 0; t < TSTEPS; t++) {
            if (t) {
                h += d0s[t] * w0 + d1s[t] * w1 + dds[t] * wdl + dchs[t] * wch;
                int c = chgs[t];                // block-uniform branch
                if (c >= 0) h += Wx[(size_t)(c & 255) * HID + j] - Wx[(size_t)(c >> 8) * HID + j];
            }
            float e = __expf(-h);
            S[t * SS + tid] = (__bf16)(h * __builtin_amdgcn_rcpf(1.f + e));
        }
        __syncthreads();
        // Phase B: wave handles K range [wave*64, wave*64+64) of this j-tile
        for (int ks = 0; ks < 2; ks++) {
            int kc = wave * 64 + ks * 32 + q * 8;
            bf16x8 a0 = *(const bf16x8*)&S[l15 * SS + kc];
            bf16x8 a1 = *(const bf16x8*)&S[(16 + l15) * SS + kc];
            int kg = jt * 256 + kc;
            const __bf16* Wb = (const __bf16*)W2T;
            bf16x8 b0  = *(const bf16x8*)&Wb[(size_t)l15 * HID + kg];
            bf16x8 b1v = *(const bf16x8*)&Wb[(size_t)(16 + l15) * HID + kg];
            bf16x8 b2v = *(const bf16x8*)&Wb[(size_t)(32 + l15) * HID + kg];
            acc[0][0] = __builtin_amdgcn_mfma_f32_16x16x32_bf16(a0, b0,  acc[0][0], 0, 0, 0);
            acc[0][1] = __builtin_amdgcn_mfma_f32_16x16x32_bf16(a0, b1v, acc[0][1], 0, 0, 0);
            acc[0][2] = __builtin_amdgcn_mfma_f32_16x16x32_bf16(a0, b2v, acc[0][2], 0, 0, 0);
            acc[1][0] = __builtin_amdgcn_mfma_f32_16x16x32_bf16(a1, b0,  acc[1][0], 0, 0, 0);
            acc[1][1] = __builtin_amdgcn_mfma_f32_16x16x32_bf16(a1, b1v, acc[1][1], 0, 0, 0);
            acc[1][2] = __builtin_amdgcn_mfma_f32_16x16x32_bf16(a1, b2v, acc[1][2], 0, 0, 0);
        }
    }
    // cross-wave reduction of logits partials (C/D layout: col=l15, row=q*4+r)
    for (int mt = 0; mt < 2; mt++)
        for (int nt = 0; nt < 3; nt++)
            for (int r = 0; r < 4; r++) {
                int t = mt * 16 + q * 4 + r;
                if (t < TSTEPS)
                    logitsP[(wave * TSTEPS + t) * 48 + nt * 16 + l15] = acc[mt][nt][r];
            }
    __syncthreads();
    for (int e = tid; e < TSTEPS * 48; e += 256)
        logitsF[e] = logitsP[e] + logitsP[960 + e] + logitsP[1920 + e] + logitsP[2880 + e];
    __syncthreads();
    if (tid < TSTEPS) {
        int t = tid;
        float mx = -1e30f;
        for (int k = 0; k < NA; k++) mx = fmaxf(mx, logitsF[t * 48 + k] + b2[k]);
        float sum = 0.f;
        for (int k = 0; k < NA; k++) sum += __expf(logitsF[t * 48 + k] + b2[k] - mx);
        int dac = dacsS[t];
        float ld = logitsF[t * 48 + dac] + b2[dac];
        float ce = -(ld - mx - logf(sum));
        ceArr[t] = alivesS[t] ? ce : 0.f;
        afArr[t] = (float)alivesS[t];
    }
    __syncthreads();
    if (tid == 0) {
        float s = 0.f, a = 0.f;
        for (int t = 0; t < TSTEPS; t++) { s += ceArr[t]; a += afArr[t]; }
        loss_out[b] = s / a;
    }
}

// ---------------------------------------------------------------------------
// Kernel 6: deterministic final reduction over 4096 per-b losses
// ---------------------------------------------------------------------------
__global__ void reduce_loss(const float* __restrict__ loss, float* __restrict__ out) {
    int tid = threadIdx.x;  // 256
    float s = 0.f;
    for (int i = tid; i < BATCH; i += 256) s += loss[i];
    for (int off = 32; off > 0; off >>= 1) s += __shfl_down(s, off, 64);
    __shared__ float wsum[4];
    if ((tid & 63) == 0) wsum[tid >> 6] = s;
    __syncthreads();
    if (tid == 0) out[0] = (wsum[0] + wsum[1] + wsum[2] + wsum[3]) * (1.0f / (float)BATCH);
}

// ---------------------------------------------------------------------------
extern "C" void kernel_launch(void* const* d_in, const int* in_sizes, int n_in,
                              void* d_out, int out_size, void* d_ws, size_t ws_size,
                              hipStream_t stream) {
    const float* fc_input = (const float*)d_in[0];
    const float* camera   = (const float*)d_in[1];
    const int*   fb       = (const int*)d_in[2];
    const int*   lr       = (const int*)d_in[3];
    const int*   jp       = (const int*)d_in[4];
    const int*   ss       = (const int*)d_in[5];
    const int*   at       = (const int*)d_in[6];
    const float* W1       = (const float*)d_in[7];
    const float* b1       = (const float*)d_in[8];
    const float* W2       = (const float*)d_in[9];
    const float* b2       = (const float*)d_in[10];
    float* out = (float*)d_out;

    char* ws = (char*)d_ws;
    unsigned short* Ab   = (unsigned short*)(ws);                       //  8,388,608 B (dead after gemm_base)
    unsigned short* Wt   = (unsigned short*)(ws + 8388608);             //  4,194,304 B
    float*          baseB= (float*)(ws + 12582912);                     // 33,554,432 B
    StepMeta*       meta = (StepMeta*)(ws + 46137344);                  //  2,621,440 B
    float*          lossB= (float*)(ws + 48758784);                     //     16,384 B
    unsigned short* W2T  = Ab;  // aliases Ab; written only after gemm_base consumed Ab

    scan_kernel<<<BATCH / 256, 256, 0, stream>>>(camera, fb, lr, jp, ss, at, meta);
    convert_fc<<<(BATCH * NI / 4) / 256, 256, 0, stream>>>(fc_input, Ab);
    transpose_w1<<<dim3(NI / 32, HID / 32), dim3(32, 8), 0, stream>>>(W1, Wt);
    gemm_base<<<dim3(HID / 128, BATCH / 128), 256, 0, stream>>>(Ab, Wt, W1, b1, baseB);
    convert_w2<<<HID / 256, 256, 0, stream>>>(W2, W2T);
    fused_mlp<<<BATCH, 256, 0, stream>>>(baseB, W1, W2T, b2, meta, lossB);
    reduce_loss<<<1, 256, 0, stream>>>(lossB, out);
}

// Round 3
// 281.955 us; speedup vs baseline: 3.0569x; 1.1527x over previous
//
#include <hip/hip_runtime.h>

// Problem constants
#define BATCH 4096
#define NI 1024
#define HID 2048
#define TSTEPS 20
#define NA 45
#define TW 512    // fused j-tile width
#define SROW 520  // S row stride in bf16 elems (512 + 8 pad)

typedef __bf16 bf16x8 __attribute__((ext_vector_type(8)));
typedef float floatx4 __attribute__((ext_vector_type(4)));

struct StepMeta {
    float ac0, ac1, delta, chosen;
    int chg;    // (oldCol<<8)|newCol applied entering this step, or -1
    int dac, alive, pad;
};

__device__ __forceinline__ unsigned short f2bf(float x) {
    union { float f; unsigned int u; } un; un.f = x;
    unsigned int r = un.u + 0x7FFFu + ((un.u >> 16) & 1u);
    return (unsigned short)(r >> 16);
}

// ---------------------------------------------------------------------------
// Kernel 1: per-batch-element 20-step state machine (exact fp32 replication).
// Emits per-step absolute state + the one-hot column swap (chg) applied since
// the previous step (at most ONE discrete change per step by construction).
// x-column offsets of the extras block: ac0=0 ac1=1 fb=2..4 lr=5..7 jp=8..9
// ss=10..13 at=14..45 delta=46 chosen=47.
// ---------------------------------------------------------------------------
__global__ void scan_kernel(const float* __restrict__ camera,
                            const int* __restrict__ fb_in, const int* __restrict__ lr_in,
                            const int* __restrict__ jp_in, const int* __restrict__ ss_in,
                            const int* __restrict__ at_in, StepMeta* __restrict__ meta) {
    int b = blockIdx.x * 256 + threadIdx.x;
    if (b >= BATCH) return;
    float cam0 = camera[2 * b], cam1 = camera[2 * b + 1];
    int afb = fb_in[b], alr = lr_in[b], ajp = jp_in[b], ass = ss_in[b], aat = at_in[b];
    float ac0 = 0.f, ac1 = 0.f, delta = 0.0625f;  // MIN_DELTA = 0.5/8
    int rfb = 0, rlr = 0, rjp = 0, rss = 0, rat = 0;
    bool chosen = false, commited = false;
    int cam_steps = 0;
    int chgPending = -1;
    bool camzero = (fabsf(cam0) < 1e-5f) && (fabsf(cam1) < 1e-5f);
    for (int t = 0; t < TSTEPS; t++) {
        StepMeta m;
        m.ac0 = ac0; m.ac1 = ac1; m.delta = delta; m.chosen = chosen ? 1.f : 0.f;
        m.chg = chgPending; chgPending = -1;
        m.alive = commited ? 0 : 1;
        bool commit = (camzero || cam_steps >= 6) &&
                      rfb == afb && rlr == alr && rjp == ajp && rss == ass && rat == aat;
        int dac = 0; bool modified = commit;
        if (!modified && rfb != afb) { dac = (afb == 0 ? rfb - 1 + 6  : afb - 1 + 6 ); chgPending = ((2  + rfb) << 8) | (2  + afb); rfb = afb; modified = true; }
        if (!modified && rlr != alr) { dac = (alr == 0 ? rlr - 1 + 8  : alr - 1 + 8 ); chgPending = ((5  + rlr) << 8) | (5  + alr); rlr = alr; modified = true; }
        if (!modified && rjp != ajp) { dac = (ajp == 0 ? rjp - 1 + 10 : ajp - 1 + 10); chgPending = ((8  + rjp) << 8) | (8  + ajp); rjp = ajp; modified = true; }
        if (!modified && rss != ass) { dac = (ass == 0 ? rss - 1 + 11 : ass - 1 + 11); chgPending = ((10 + rss) << 8) | (10 + ass); rss = ass; modified = true; }
        if (!modified && rat != aat) { dac = (aat == 0 ? rat - 1 + 14 : aat - 1 + 14); chgPending = ((14 + rat) << 8) | (14 + aat); rat = aat; modified = true; }
        // NOTE: reference compares BOTH cam0 and cam1 against ac0 (replicated as-is)
        if (!modified && !chosen &&
            (fabsf(cam0 - ac0) > delta * 2.f || fabsf(cam1 - ac0) > delta * 2.f)) {
            dac = 5; delta = fminf(delta * 2.f, 0.5f); modified = true;
        }
        if (!modified) {
            bool incX = cam0 >= ac0, incY = cam1 >= ac1;
            dac = 1 + (incX ? 1 : 0) + (incY ? 2 : 0);
            ac0 += incX ? delta : -delta;
            ac1 += incY ? delta : -delta;
            delta *= 0.5f;
            chosen = true;
            cam_steps++;
        }
        commited = commited || commit;
        m.dac = dac; m.pad = 0;
        meta[b * TSTEPS + t] = m;
    }
}

// ---------------------------------------------------------------------------
// Kernel 2: fc_input fp32 -> bf16 (elementwise, vectorized)
// ---------------------------------------------------------------------------
__global__ void convert_fc(const float* __restrict__ fc, unsigned short* __restrict__ Ab) {
    int idx = blockIdx.x * 256 + threadIdx.x;  // covers BATCH*NI/4
    float4 v = ((const float4*)fc)[idx];
    ushort4 o;
    o.x = f2bf(v.x); o.y = f2bf(v.y); o.z = f2bf(v.z); o.w = f2bf(v.w);
    ((ushort4*)Ab)[idx] = o;
}

// ---------------------------------------------------------------------------
// Kernel 3: W1[0:1024][2048] fp32 -> bf16, transposed to Wt[2048][1024]
// ---------------------------------------------------------------------------
__global__ void transpose_w1(const float* __restrict__ W1, unsigned short* __restrict__ Wt) {
    __shared__ float tile[32][33];
    int k0 = blockIdx.x * 32, n0 = blockIdx.y * 32;
    int tx = threadIdx.x, ty = threadIdx.y;  // (32, 8)
    for (int i = 0; i < 4; i++)
        tile[ty + 8 * i][tx] = W1[(size_t)(k0 + ty + 8 * i) * HID + n0 + tx];
    __syncthreads();
    for (int i = 0; i < 4; i++) {
        int n = ty + 8 * i;
        Wt[(size_t)(n0 + n) * NI + k0 + tx] = f2bf(tile[tx][n]);
    }
}

// ---------------------------------------------------------------------------
// Kernel 3b: W2[2048][45] fp32 -> bf16 transposed W2T[48][2048], rows 45..47
// zero-padded (MFMA N-tile padding).
// ---------------------------------------------------------------------------
__global__ void convert_w2(const float* __restrict__ W2, unsigned short* __restrict__ W2T) {
    int k = blockIdx.x * 256 + threadIdx.x;  // 0..2047
    for (int n = 0; n < 48; n++)
        W2T[(size_t)n * HID + k] = (n < NA) ? f2bf(W2[(size_t)k * NA + n]) : (unsigned short)0;
}

// ---------------------------------------------------------------------------
// Kernel 4: base[4096][2048] = A @ W1[:1024] (bf16 MFMA, m97-style
// global_load_lds staging, unpadded 128x32 LDS tiles) with the t=0-constant
// epilogue folded in: + b1 + initial one-hot rows (2,5,8,10,14) + 0.0625*w_delta.
// Staging map: chunk c = i*256+tid (i=0,1); row=c>>2, quarter=c&3; LDS byte
// offset c*16 == wave-uniform base + lane*16 (global_load_lds requirement).
// ---------------------------------------------------------------------------
__global__ __launch_bounds__(256) void gemm_base(const unsigned short* __restrict__ Ab,
                                                 const unsigned short* __restrict__ Wt,
                                                 const float* __restrict__ W1,
                                                 const float* __restrict__ b1,
                                                 float* __restrict__ C) {
    __shared__ __align__(16) __bf16 At[128 * 32];
    __shared__ __align__(16) __bf16 Bt[128 * 32];
    int bn = blockIdx.x, bm = blockIdx.y;
    int m0 = bm * 128, n0 = bn * 128;
    int tid = threadIdx.x;
    int wave = tid >> 6, lane = tid & 63;
    int wr = wave >> 1, wc = wave & 1;
    int l15 = lane & 15, q = lane >> 4;
    floatx4 acc[4][4];
    for (int a = 0; a < 4; a++) for (int c = 0; c < 4; c++) acc[a][c] = (floatx4){0.f, 0.f, 0.f, 0.f};
    for (int k0 = 0; k0 < NI; k0 += 32) {
        __syncthreads();
#pragma unroll
        for (int i = 0; i < 2; i++) {
            int c = i * 256 + tid;
            int row = c >> 2, quarter = c & 3;
            const unsigned short* gA = &Ab[(size_t)(m0 + row) * NI + k0 + quarter * 8];
            const unsigned short* gB = &Wt[(size_t)(n0 + row) * NI + k0 + quarter * 8];
            __builtin_amdgcn_global_load_lds(
                (const __attribute__((address_space(1))) unsigned int*)gA,
                (__attribute__((address_space(3))) unsigned int*)&At[c * 8], 16, 0, 0);
            __builtin_amdgcn_global_load_lds(
                (const __attribute__((address_space(1))) unsigned int*)gB,
                (__attribute__((address_space(3))) unsigned int*)&Bt[c * 8], 16, 0, 0);
        }
        __syncthreads();
        bf16x8 af[4], bf[4];
        for (int mr = 0; mr < 4; mr++)
            af[mr] = *(const bf16x8*)&At[(wr * 64 + mr * 16 + l15) * 32 + q * 8];
        for (int nc = 0; nc < 4; nc++)
            bf[nc] = *(const bf16x8*)&Bt[(wc * 64 + nc * 16 + l15) * 32 + q * 8];
        for (int mr = 0; mr < 4; mr++)
            for (int nc = 0; nc < 4; nc++)
                acc[mr][nc] = __builtin_amdgcn_mfma_f32_16x16x32_bf16(af[mr], bf[nc], acc[mr][nc], 0, 0, 0);
    }
    for (int nc = 0; nc < 4; nc++) {
        int col = n0 + wc * 64 + nc * 16 + l15;
        const float* We = W1 + (size_t)NI * HID + col;
        float cv = b1[col] + We[2 * HID] + We[5 * HID] + We[8 * HID] + We[10 * HID]
                 + We[14 * HID] + 0.0625f * We[46 * HID];
        for (int mr = 0; mr < 4; mr++)
            for (int r = 0; r < 4; r++) {
                int row = m0 + wr * 64 + mr * 16 + q * 4 + r;
                C[(size_t)row * HID + col] = acc[mr][nc][r] + cv;
            }
    }
}

// ---------------------------------------------------------------------------
// Kernel 5: fused per-b MLP + CE. One block per b, 256 threads, 2 j per thread.
// Phase A (absolute-state, chain-free): h[t] = base + ac0[t]*w0 + ac1[t]*w1
// + (delta[t]-d0)*wdl + chosen[t]*wch + sw[t]; fully unrolled over t (ILP).
// silu -> bf16 S tile (20x512) in LDS. Phase B: MFMA logits += S @ W2T-frags
// (K split 128/wave, fp32 accum across 4 j-tiles), cross-wave reduce, CE.
// Cross-wave partials alias S (dead by then) to stay at 4 blocks/CU.
// ---------------------------------------------------------------------------
__global__ __launch_bounds__(256) void fused_mlp(const float* __restrict__ base,
                                                 const float* __restrict__ W1,
                                                 const unsigned short* __restrict__ W2T,
                                                 const float* __restrict__ b2,
                                                 const StepMeta* __restrict__ meta,
                                                 float* __restrict__ loss_out) {
    __shared__ __align__(16) __bf16 S[32 * SROW];        // 33,280 B; rows 20..31 zero
    __shared__ __align__(16) float logitsF[TSTEPS * 48];
    __shared__ __align__(16) float4 u4s[TSTEPS];         // (ac0, ac1, delta-d0, chosen)
    __shared__ int chgs[TSTEPS], dacsS[TSTEPS], alivesS[TSTEPS];
    __shared__ float ceArr[TSTEPS], afArr[TSTEPS];

    int b = blockIdx.x, tid = threadIdx.x;
    int wave = tid >> 6, lane = tid & 63, l15 = lane & 15, q = lane >> 4;

    // zero the MFMA padding rows 20..31 (bytes [20*SROW*2, 32*SROW*2))
    {
        uint4* z = (uint4*)&S[20 * SROW];
        for (int i = tid; i < 12 * SROW * 2 / 16; i += 256) z[i] = make_uint4(0, 0, 0, 0);
    }
    if (tid < TSTEPS) {
        StepMeta m = meta[b * TSTEPS + tid];
        u4s[tid] = make_float4(m.ac0, m.ac1, m.delta - 0.0625f, m.chosen);
        chgs[tid] = m.chg; dacsS[tid] = m.dac; alivesS[tid] = m.alive;
    }
    __syncthreads();

    const float* Wx = W1 + (size_t)NI * HID;
    floatx4 acc[2][3];
    for (int a = 0; a < 2; a++) for (int c = 0; c < 3; c++) acc[a][c] = (floatx4){0.f, 0.f, 0.f, 0.f};

    for (int jt = 0; jt < 4; jt++) {
        if (jt) __syncthreads();                 // phase-B readers of prev tile done
        int j = jt * TW + 2 * tid;
        float2 w0  = *(const float2*)&Wx[j];
        float2 w1  = *(const float2*)&Wx[HID + j];
        float2 wdl = *(const float2*)&Wx[46 * HID + j];
        float2 wch = *(const float2*)&Wx[47 * HID + j];
        float2 hb  = *(const float2*)&base[(size_t)b * HID + j];  // incl. b1 + t0 consts
        float sw0 = 0.f, sw1 = 0.f;
#pragma unroll
        for (int t = 0; t < TSTEPS; t++) {
            int c = chgs[t];                     // block-uniform branch
            if (c >= 0) {
                float2 rn = *(const float2*)&Wx[(size_t)(c & 255) * HID + j];
                float2 ro = *(const float2*)&Wx[(size_t)(c >> 8) * HID + j];
                sw0 += rn.x - ro.x; sw1 += rn.y - ro.y;
            }
            float4 u = u4s[t];
            float h0 = hb.x + sw0 + u.x * w0.x + u.y * w1.x + u.z * wdl.x + u.w * wch.x;
            float h1 = hb.y + sw1 + u.x * w0.y + u.y * w1.y + u.z * wdl.y + u.w * wch.y;
            float s0 = h0 * __builtin_amdgcn_rcpf(1.f + __expf(-h0));
            float s1 = h1 * __builtin_amdgcn_rcpf(1.f + __expf(-h1));
            union { unsigned int u32; unsigned short s16[2]; } pk;
            pk.s16[0] = f2bf(s0); pk.s16[1] = f2bf(s1);
            *(unsigned int*)&S[t * SROW + 2 * tid] = pk.u32;
        }
        __syncthreads();
        // Phase B: wave handles K range [wave*128, wave*128+128) of this j-tile
        const __bf16* Wb = (const __bf16*)W2T;
#pragma unroll
        for (int ks = 0; ks < 4; ks++) {
            int kc = wave * 128 + ks * 32 + q * 8;
            bf16x8 a0 = *(const bf16x8*)&S[l15 * SROW + kc];
            bf16x8 a1 = *(const bf16x8*)&S[(16 + l15) * SROW + kc];
            int kg = jt * TW + kc;
            bf16x8 b0  = *(const bf16x8*)&Wb[(size_t)l15 * HID + kg];
            bf16x8 b1v = *(const bf16x8*)&Wb[(size_t)(16 + l15) * HID + kg];
            bf16x8 b2v = *(const bf16x8*)&Wb[(size_t)(32 + l15) * HID + kg];
            acc[0][0] = __builtin_amdgcn_mfma_f32_16x16x32_bf16(a0, b0,  acc[0][0], 0, 0, 0);
            acc[0][1] = __builtin_amdgcn_mfma_f32_16x16x32_bf16(a0, b1v, acc[0][1], 0, 0, 0);
            acc[0][2] = __builtin_amdgcn_mfma_f32_16x16x32_bf16(a0, b2v, acc[0][2], 0, 0, 0);
            acc[1][0] = __builtin_amdgcn_mfma_f32_16x16x32_bf16(a1, b0,  acc[1][0], 0, 0, 0);
            acc[1][1] = __builtin_amdgcn_mfma_f32_16x16x32_bf16(a1, b1v, acc[1][1], 0, 0, 0);
            acc[1][2] = __builtin_amdgcn_mfma_f32_16x16x32_bf16(a1, b2v, acc[1][2], 0, 0, 0);
        }
    }
    __syncthreads();
    // cross-wave reduction of logits partials (C/D layout: col=l15, row=q*4+r)
    float* logitsP = (float*)S;   // S is dead; 4*20*48*4 = 15,360 B <= 33,280 B
    for (int mt = 0; mt < 2; mt++)
        for (int nt = 0; nt < 3; nt++)
            for (int r = 0; r < 4; r++) {
                int t = mt * 16 + q * 4 + r;
                if (t < TSTEPS)
                    logitsP[(wave * TSTEPS + t) * 48 + nt * 16 + l15] = acc[mt][nt][r];
            }
    __syncthreads();
    for (int e = tid; e < TSTEPS * 48; e += 256)
        logitsF[e] = logitsP[e] + logitsP[960 + e] + logitsP[1920 + e] + logitsP[2880 + e];
    __syncthreads();
    if (tid < TSTEPS) {
        int t = tid;
        float mx = -1e30f;
        for (int k = 0; k < NA; k++) mx = fmaxf(mx, logitsF[t * 48 + k] + b2[k]);
        float sum = 0.f;
        for (int k = 0; k < NA; k++) sum += __expf(logitsF[t * 48 + k] + b2[k] - mx);
        int dac = dacsS[t];
        float ld = logitsF[t * 48 + dac] + b2[dac];
        float ce = -(ld - mx - logf(sum));
        ceArr[t] = alivesS[t] ? ce : 0.f;
        afArr[t] = (float)alivesS[t];
    }
    __syncthreads();
    if (tid == 0) {
        float s = 0.f, a = 0.f;
        for (int t = 0; t < TSTEPS; t++) { s += ceArr[t]; a += afArr[t]; }
        loss_out[b] = s / a;
    }
}

// ---------------------------------------------------------------------------
// Kernel 6: deterministic final reduction over 4096 per-b losses
// ---------------------------------------------------------------------------
__global__ void reduce_loss(const float* __restrict__ loss, float* __restrict__ out) {
    int tid = threadIdx.x;  // 256
    float s = 0.f;
    for (int i = tid; i < BATCH; i += 256) s += loss[i];
    for (int off = 32; off > 0; off >>= 1) s += __shfl_down(s, off, 64);
    __shared__ float wsum[4];
    if ((tid & 63) == 0) wsum[tid >> 6] = s;
    __syncthreads();
    if (tid == 0) out[0] = (wsum[0] + wsum[1] + wsum[2] + wsum[3]) * (1.0f / (float)BATCH);
}

// ---------------------------------------------------------------------------
extern "C" void kernel_launch(void* const* d_in, const int* in_sizes, int n_in,
                              void* d_out, int out_size, void* d_ws, size_t ws_size,
                              hipStream_t stream) {
    const float* fc_input = (const float*)d_in[0];
    const float* camera   = (const float*)d_in[1];
    const int*   fb       = (const int*)d_in[2];
    const int*   lr       = (const int*)d_in[3];
    const int*   jp       = (const int*)d_in[4];
    const int*   ss       = (const int*)d_in[5];
    const int*   at       = (const int*)d_in[6];
    const float* W1       = (const float*)d_in[7];
    const float* b1       = (const float*)d_in[8];
    const float* W2       = (const float*)d_in[9];
    const float* b2       = (const float*)d_in[10];
    float* out = (float*)d_out;

    char* ws = (char*)d_ws;
    unsigned short* Ab   = (unsigned short*)(ws);                       //  8,388,608 B (dead after gemm_base)
    unsigned short* Wt   = (unsigned short*)(ws + 8388608);             //  4,194,304 B
    float*          baseB= (float*)(ws + 12582912);                     // 33,554,432 B
    StepMeta*       meta = (StepMeta*)(ws + 46137344);                  //  2,621,440 B
    float*          lossB= (float*)(ws + 48758784);                     //     16,384 B
    unsigned short* W2T  = Ab;  // aliases Ab; written only after gemm_base consumed Ab

    scan_kernel<<<BATCH / 256, 256, 0, stream>>>(camera, fb, lr, jp, ss, at, meta);
    convert_fc<<<(BATCH * NI / 4) / 256, 256, 0, stream>>>(fc_input, Ab);
    transpose_w1<<<dim3(NI / 32, HID / 32), dim3(32, 8), 0, stream>>>(W1, Wt);
    gemm_base<<<dim3(HID / 128, BATCH / 128), 256, 0, stream>>>(Ab, Wt, W1, b1, baseB);
    convert_w2<<<HID / 256, 256, 0, stream>>>(W2, W2T);
    fused_mlp<<<BATCH, 256, 0, stream>>>(baseB, W1, W2T, b2, meta, lossB);
    reduce_loss<<<1, 256, 0, stream>>>(lossB, out);
}

// Round 4
// 261.545 us; speedup vs baseline: 3.2954x; 1.0780x over previous
//
#include <hip/hip_runtime.h>

// Problem constants
#define BATCH 4096
#define NI 1024
#define HID 2048
#define TSTEPS 20
#define NA 45
#define TW 512    // fused j-tile width
#define SROW 520  // S row stride in bf16 elems (512 + 8 pad)

typedef __bf16 bf16x8 __attribute__((ext_vector_type(8)));
typedef float floatx4 __attribute__((ext_vector_type(4)));

struct StepMeta {
    float ac0, ac1, delta, chosen;
    int chg;    // (oldCol<<8)|newCol applied entering this step, or -1
    int dac, alive, pad;
};

__device__ __forceinline__ unsigned short f2bf(float x) {
    union { float f; unsigned int u; } un; un.f = x;
    unsigned int r = un.u + 0x7FFFu + ((un.u >> 16) & 1u);
    return (unsigned short)(r >> 16);
}

// ---------------------------------------------------------------------------
// Kernel 1: per-batch-element 20-step state machine (exact fp32 replication).
// Emits per-step absolute state + the one-hot column swap (chg) applied since
// the previous step (at most ONE discrete change per step by construction).
// x-column offsets of the extras block: ac0=0 ac1=1 fb=2..4 lr=5..7 jp=8..9
// ss=10..13 at=14..45 delta=46 chosen=47.
// ---------------------------------------------------------------------------
__global__ void scan_kernel(const float* __restrict__ camera,
                            const int* __restrict__ fb_in, const int* __restrict__ lr_in,
                            const int* __restrict__ jp_in, const int* __restrict__ ss_in,
                            const int* __restrict__ at_in, StepMeta* __restrict__ meta) {
    int b = blockIdx.x * 256 + threadIdx.x;
    if (b >= BATCH) return;
    float cam0 = camera[2 * b], cam1 = camera[2 * b + 1];
    int afb = fb_in[b], alr = lr_in[b], ajp = jp_in[b], ass = ss_in[b], aat = at_in[b];
    float ac0 = 0.f, ac1 = 0.f, delta = 0.0625f;  // MIN_DELTA = 0.5/8
    int rfb = 0, rlr = 0, rjp = 0, rss = 0, rat = 0;
    bool chosen = false, commited = false;
    int cam_steps = 0;
    int chgPending = -1;
    bool camzero = (fabsf(cam0) < 1e-5f) && (fabsf(cam1) < 1e-5f);
    for (int t = 0; t < TSTEPS; t++) {
        StepMeta m;
        m.ac0 = ac0; m.ac1 = ac1; m.delta = delta; m.chosen = chosen ? 1.f : 0.f;
        m.chg = chgPending; chgPending = -1;
        m.alive = commited ? 0 : 1;
        bool commit = (camzero || cam_steps >= 6) &&
                      rfb == afb && rlr == alr && rjp == ajp && rss == ass && rat == aat;
        int dac = 0; bool modified = commit;
        if (!modified && rfb != afb) { dac = (afb == 0 ? rfb - 1 + 6  : afb - 1 + 6 ); chgPending = ((2  + rfb) << 8) | (2  + afb); rfb = afb; modified = true; }
        if (!modified && rlr != alr) { dac = (alr == 0 ? rlr - 1 + 8  : alr - 1 + 8 ); chgPending = ((5  + rlr) << 8) | (5  + alr); rlr = alr; modified = true; }
        if (!modified && rjp != ajp) { dac = (ajp == 0 ? rjp - 1 + 10 : ajp - 1 + 10); chgPending = ((8  + rjp) << 8) | (8  + ajp); rjp = ajp; modified = true; }
        if (!modified && rss != ass) { dac = (ass == 0 ? rss - 1 + 11 : ass - 1 + 11); chgPending = ((10 + rss) << 8) | (10 + ass); rss = ass; modified = true; }
        if (!modified && rat != aat) { dac = (aat == 0 ? rat - 1 + 14 : aat - 1 + 14); chgPending = ((14 + rat) << 8) | (14 + aat); rat = aat; modified = true; }
        // NOTE: reference compares BOTH cam0 and cam1 against ac0 (replicated as-is)
        if (!modified && !chosen &&
            (fabsf(cam0 - ac0) > delta * 2.f || fabsf(cam1 - ac0) > delta * 2.f)) {
            dac = 5; delta = fminf(delta * 2.f, 0.5f); modified = true;
        }
        if (!modified) {
            bool incX = cam0 >= ac0, incY = cam1 >= ac1;
            dac = 1 + (incX ? 1 : 0) + (incY ? 2 : 0);
            ac0 += incX ? delta : -delta;
            ac1 += incY ? delta : -delta;
            delta *= 0.5f;
            chosen = true;
            cam_steps++;
        }
        commited = commited || commit;
        m.dac = dac; m.pad = 0;
        meta[b * TSTEPS + t] = m;
    }
}

// ---------------------------------------------------------------------------
// Kernel 2 (merged prep): convert_fc (blocks [0,4096)), transpose_w1
// (blocks [4096,6144)), convert_w2 (blocks [6144,6152)) — one launch.
// ---------------------------------------------------------------------------
__global__ void prep_kernel(const float* __restrict__ fc, unsigned short* __restrict__ Ab,
                            const float* __restrict__ W1, unsigned short* __restrict__ Wt,
                            const float* __restrict__ W2, unsigned short* __restrict__ W2T) {
    __shared__ float tile[32][33];
    int bid = blockIdx.x, tid = threadIdx.x;
    if (bid < 4096) {
        int idx = bid * 256 + tid;  // covers BATCH*NI/4
        float4 v = ((const float4*)fc)[idx];
        ushort4 o;
        o.x = f2bf(v.x); o.y = f2bf(v.y); o.z = f2bf(v.z); o.w = f2bf(v.w);
        ((ushort4*)Ab)[idx] = o;
    } else if (bid < 6144) {
        int b2 = bid - 4096;
        int k0 = (b2 & 31) * 32, n0 = (b2 >> 5) * 32;
        int tx = tid & 31, ty = tid >> 5;  // (32, 8)
        for (int i = 0; i < 4; i++)
            tile[ty + 8 * i][tx] = W1[(size_t)(k0 + ty + 8 * i) * HID + n0 + tx];
        __syncthreads();
        for (int i = 0; i < 4; i++) {
            int n = ty + 8 * i;
            Wt[(size_t)(n0 + n) * NI + k0 + tx] = f2bf(tile[tx][n]);
        }
    } else {
        int k = (bid - 6144) * 256 + tid;  // 0..2047
        for (int n = 0; n < 48; n++)
            W2T[(size_t)n * HID + k] = (n < NA) ? f2bf(W2[(size_t)k * NA + n]) : (unsigned short)0;
    }
}

// ---------------------------------------------------------------------------
// Kernel 4: base[4096][2048] = A @ W1[:1024] (bf16 MFMA, global_load_lds
// staging, unpadded 128x32 LDS tiles) with the t=0-constant epilogue folded
// in: + b1 + initial one-hot rows (2,5,8,10,14) + 0.0625*w_delta.
// ---------------------------------------------------------------------------
__global__ __launch_bounds__(256) void gemm_base(const unsigned short* __restrict__ Ab,
                                                 const unsigned short* __restrict__ Wt,
                                                 const float* __restrict__ W1,
                                                 const float* __restrict__ b1,
                                                 float* __restrict__ C) {
    __shared__ __align__(16) __bf16 At[128 * 32];
    __shared__ __align__(16) __bf16 Bt[128 * 32];
    int bn = blockIdx.x, bm = blockIdx.y;
    int m0 = bm * 128, n0 = bn * 128;
    int tid = threadIdx.x;
    int wave = tid >> 6, lane = tid & 63;
    int wr = wave >> 1, wc = wave & 1;
    int l15 = lane & 15, q = lane >> 4;
    floatx4 acc[4][4];
    for (int a = 0; a < 4; a++) for (int c = 0; c < 4; c++) acc[a][c] = (floatx4){0.f, 0.f, 0.f, 0.f};
    for (int k0 = 0; k0 < NI; k0 += 32) {
        __syncthreads();
#pragma unroll
        for (int i = 0; i < 2; i++) {
            int c = i * 256 + tid;
            int row = c >> 2, quarter = c & 3;
            const unsigned short* gA = &Ab[(size_t)(m0 + row) * NI + k0 + quarter * 8];
            const unsigned short* gB = &Wt[(size_t)(n0 + row) * NI + k0 + quarter * 8];
            __builtin_amdgcn_global_load_lds(
                (const __attribute__((address_space(1))) unsigned int*)gA,
                (__attribute__((address_space(3))) unsigned int*)&At[c * 8], 16, 0, 0);
            __builtin_amdgcn_global_load_lds(
                (const __attribute__((address_space(1))) unsigned int*)gB,
                (__attribute__((address_space(3))) unsigned int*)&Bt[c * 8], 16, 0, 0);
        }
        __syncthreads();
        bf16x8 af[4], bf[4];
        for (int mr = 0; mr < 4; mr++)
            af[mr] = *(const bf16x8*)&At[(wr * 64 + mr * 16 + l15) * 32 + q * 8];
        for (int nc = 0; nc < 4; nc++)
            bf[nc] = *(const bf16x8*)&Bt[(wc * 64 + nc * 16 + l15) * 32 + q * 8];
        for (int mr = 0; mr < 4; mr++)
            for (int nc = 0; nc < 4; nc++)
                acc[mr][nc] = __builtin_amdgcn_mfma_f32_16x16x32_bf16(af[mr], bf[nc], acc[mr][nc], 0, 0, 0);
    }
    for (int nc = 0; nc < 4; nc++) {
        int col = n0 + wc * 64 + nc * 16 + l15;
        const float* We = W1 + (size_t)NI * HID + col;
        float cv = b1[col] + We[2 * HID] + We[5 * HID] + We[8 * HID] + We[10 * HID]
                 + We[14 * HID] + 0.0625f * We[46 * HID];
        for (int mr = 0; mr < 4; mr++)
            for (int r = 0; r < 4; r++) {
                int row = m0 + wr * 64 + mr * 16 + q * 4 + r;
                C[(size_t)row * HID + col] = acc[mr][nc][r] + cv;
            }
    }
}

// ---------------------------------------------------------------------------
// Kernel 5: fused per-b MLP + CE. One block per b, 256 threads, 2 j per thread.
// Phase A: h[t] = base + u[t]·w + sw[t], sw from PRE-LOADED swap-row diffs
// (all ≤10 global loads hoisted to tile start -> one L2 latency, not ~3.5
// serialized). silu -> bf16 S (20x512) in LDS. Phase B: MFMA S @ W2T,
// cross-wave reduce (aliased into dead S), parallel 240-thread CE.
// ---------------------------------------------------------------------------
__global__ __launch_bounds__(256) void fused_mlp(const float* __restrict__ base,
                                                 const float* __restrict__ W1,
                                                 const unsigned short* __restrict__ W2T,
                                                 const float* __restrict__ b2,
                                                 const StepMeta* __restrict__ meta,
                                                 float* __restrict__ loss_out) {
    __shared__ __align__(16) __bf16 S[32 * SROW];        // 33,280 B; rows 20..31 zero
    __shared__ __align__(16) float4 u4s[TSTEPS];         // (ac0, ac1, delta-d0, chosen)
    __shared__ int chgs[TSTEPS], dacsS[TSTEPS], alivesS[TSTEPS];
    __shared__ int swapL[5], nsS;
    __shared__ float b2s[48];
    __shared__ float ceArr[TSTEPS], afArr[TSTEPS];
    __shared__ float pmax[TSTEPS][12], psum[TSTEPS][12], mxS[TSTEPS];

    int b = blockIdx.x, tid = threadIdx.x;
    int wave = tid >> 6, lane = tid & 63, l15 = lane & 15, q = lane >> 4;

    // zero the MFMA padding rows 20..31
    {
        uint4* z = (uint4*)&S[20 * SROW];
        for (int i = tid; i < 12 * SROW * 2 / 16; i += 256) z[i] = make_uint4(0, 0, 0, 0);
    }
    if (tid < TSTEPS) {
        StepMeta m = meta[b * TSTEPS + tid];
        u4s[tid] = make_float4(m.ac0, m.ac1, m.delta - 0.0625f, m.chosen);
        chgs[tid] = m.chg; dacsS[tid] = m.dac; alivesS[tid] = m.alive;
    }
    if (tid < 48) b2s[tid] = (tid < NA) ? b2[tid] : 0.f;
    __syncthreads();
    if (tid == 0) {
        int ns = 0;
        for (int t = 0; t < TSTEPS; t++) if (chgs[t] >= 0) swapL[ns++] = chgs[t];
        nsS = ns;
        for (; ns < 5; ns++) swapL[ns] = 0;
    }
    __syncthreads();

    const float* Wx = W1 + (size_t)NI * HID;
    floatx4 acc[2][3];
    for (int a = 0; a < 2; a++) for (int c = 0; c < 3; c++) acc[a][c] = (floatx4){0.f, 0.f, 0.f, 0.f};

    int ns = __builtin_amdgcn_readfirstlane(nsS);
    int cA = __builtin_amdgcn_readfirstlane(swapL[0]);
    int cB = __builtin_amdgcn_readfirstlane(swapL[1]);
    int cC = __builtin_amdgcn_readfirstlane(swapL[2]);
    int cD = __builtin_amdgcn_readfirstlane(swapL[3]);
    int cE = __builtin_amdgcn_readfirstlane(swapL[4]);

    for (int jt = 0; jt < 4; jt++) {
        if (jt) __syncthreads();                 // phase-B readers of prev tile done
        int j = jt * TW + 2 * tid;
        // hoisted loads: w-vectors, base, and ALL swap rows (load-only branches)
        float2 w0  = *(const float2*)&Wx[j];
        float2 w1  = *(const float2*)&Wx[HID + j];
        float2 wdl = *(const float2*)&Wx[46 * HID + j];
        float2 wch = *(const float2*)&Wx[47 * HID + j];
        float2 hb  = *(const float2*)&base[(size_t)b * HID + j];  // incl. b1 + t0 consts
        float2 nA = {0,0}, oA = {0,0}, nB = {0,0}, oB = {0,0}, nC = {0,0}, oC = {0,0};
        float2 nD = {0,0}, oD = {0,0}, nE = {0,0}, oE = {0,0};
        if (ns > 0) { nA = *(const float2*)&Wx[(size_t)(cA & 255) * HID + j]; oA = *(const float2*)&Wx[(size_t)(cA >> 8) * HID + j]; }
        if (ns > 1) { nB = *(const float2*)&Wx[(size_t)(cB & 255) * HID + j]; oB = *(const float2*)&Wx[(size_t)(cB >> 8) * HID + j]; }
        if (ns > 2) { nC = *(const float2*)&Wx[(size_t)(cC & 255) * HID + j]; oC = *(const float2*)&Wx[(size_t)(cC >> 8) * HID + j]; }
        if (ns > 3) { nD = *(const float2*)&Wx[(size_t)(cD & 255) * HID + j]; oD = *(const float2*)&Wx[(size_t)(cD >> 8) * HID + j]; }
        if (ns > 4) { nE = *(const float2*)&Wx[(size_t)(cE & 255) * HID + j]; oE = *(const float2*)&Wx[(size_t)(cE >> 8) * HID + j]; }
        float dAx = nA.x - oA.x, dAy = nA.y - oA.y;
        float dBx = nB.x - oB.x, dBy = nB.y - oB.y;
        float dCx = nC.x - oC.x, dCy = nC.y - oC.y;
        float dDx = nD.x - oD.x, dDy = nD.y - oD.y;
        float dEx = nE.x - oE.x, dEy = nE.y - oE.y;
        float sw0 = 0.f, sw1 = 0.f;
        int sc = 0;
#pragma unroll
        for (int t = 0; t < TSTEPS; t++) {
            int c = __builtin_amdgcn_readfirstlane(chgs[t]);  // uniform branch
            if (c >= 0) {
                float dx = (sc == 0) ? dAx : (sc == 1) ? dBx : (sc == 2) ? dCx : (sc == 3) ? dDx : dEx;
                float dy = (sc == 0) ? dAy : (sc == 1) ? dBy : (sc == 2) ? dCy : (sc == 3) ? dDy : dEy;
                sw0 += dx; sw1 += dy; sc++;
            }
            float4 u = u4s[t];
            float h0 = hb.x + sw0 + u.x * w0.x + u.y * w1.x + u.z * wdl.x + u.w * wch.x;
            float h1 = hb.y + sw1 + u.x * w0.y + u.y * w1.y + u.z * wdl.y + u.w * wch.y;
            float s0 = h0 * __builtin_amdgcn_rcpf(1.f + __expf(-h0));
            float s1 = h1 * __builtin_amdgcn_rcpf(1.f + __expf(-h1));
            union { unsigned int u32; unsigned short s16[2]; } pk;
            pk.s16[0] = f2bf(s0); pk.s16[1] = f2bf(s1);
            *(unsigned int*)&S[t * SROW + 2 * tid] = pk.u32;
        }
        __syncthreads();
        // Phase B: wave handles K range [wave*128, wave*128+128) of this j-tile
        const __bf16* Wb = (const __bf16*)W2T;
#pragma unroll
        for (int ks = 0; ks < 4; ks++) {
            int kc = wave * 128 + ks * 32 + q * 8;
            bf16x8 a0 = *(const bf16x8*)&S[l15 * SROW + kc];
            bf16x8 a1 = *(const bf16x8*)&S[(16 + l15) * SROW + kc];
            int kg = jt * TW + kc;
            bf16x8 b0  = *(const bf16x8*)&Wb[(size_t)l15 * HID + kg];
            bf16x8 b1v = *(const bf16x8*)&Wb[(size_t)(16 + l15) * HID + kg];
            bf16x8 b2v = *(const bf16x8*)&Wb[(size_t)(32 + l15) * HID + kg];
            acc[0][0] = __builtin_amdgcn_mfma_f32_16x16x32_bf16(a0, b0,  acc[0][0], 0, 0, 0);
            acc[0][1] = __builtin_amdgcn_mfma_f32_16x16x32_bf16(a0, b1v, acc[0][1], 0, 0, 0);
            acc[0][2] = __builtin_amdgcn_mfma_f32_16x16x32_bf16(a0, b2v, acc[0][2], 0, 0, 0);
            acc[1][0] = __builtin_amdgcn_mfma_f32_16x16x32_bf16(a1, b0,  acc[1][0], 0, 0, 0);
            acc[1][1] = __builtin_amdgcn_mfma_f32_16x16x32_bf16(a1, b1v, acc[1][1], 0, 0, 0);
            acc[1][2] = __builtin_amdgcn_mfma_f32_16x16x32_bf16(a1, b2v, acc[1][2], 0, 0, 0);
        }
    }
    __syncthreads();
    // cross-wave partials into dead S (C/D layout: col=l15, row=q*4+r)
    float* logitsP = (float*)S;                  // 4*960 floats = 15,360 B
    float* logitsF = (float*)S + 4096;           // bytes 16,384..20,224
    for (int mt = 0; mt < 2; mt++)
        for (int nt = 0; nt < 3; nt++)
            for (int r = 0; r < 4; r++) {
                int t = mt * 16 + q * 4 + r;
                if (t < TSTEPS)
                    logitsP[(wave * TSTEPS + t) * 48 + nt * 16 + l15] = acc[mt][nt][r];
            }
    __syncthreads();
    int tE = tid / 12, gE = tid - tE * 12;
    if (tid < 240) {
        float4 p0 = ((const float4*)logitsP)[tid];
        float4 p1 = ((const float4*)logitsP)[240 + tid];
        float4 p2 = ((const float4*)logitsP)[480 + tid];
        float4 p3 = ((const float4*)logitsP)[720 + tid];
        float4 bb = *(const float4*)&b2s[gE * 4];
        float4 r;
        r.x = p0.x + p1.x + p2.x + p3.x + bb.x;
        r.y = p0.y + p1.y + p2.y + p3.y + bb.y;
        r.z = p0.z + p1.z + p2.z + p3.z + bb.z;
        r.w = p0.w + p1.w + p2.w + p3.w + bb.w;
        ((float4*)logitsF)[tid] = r;
        float lm = (gE == 11) ? r.x : fmaxf(fmaxf(r.x, r.y), fmaxf(r.z, r.w));
        pmax[tE][gE] = lm;
    }
    __syncthreads();
    if (tid < 240 && gE == 0) {
        float m = pmax[tE][0];
        for (int i = 1; i < 12; i++) m = fmaxf(m, pmax[tE][i]);
        mxS[tE] = m;
    }
    __syncthreads();
    if (tid < 240) {
        float m = mxS[tE];
        float4 v = ((const float4*)logitsF)[tid];
        float s;
        if (gE == 11) s = __expf(v.x - m);
        else s = __expf(v.x - m) + __expf(v.y - m) + __expf(v.z - m) + __expf(v.w - m);
        psum[tE][gE] = s;
    }
    __syncthreads();
    if (tid < TSTEPS) {
        float ssum = 0.f;
        for (int i = 0; i < 12; i++) ssum += psum[tid][i];
        float m = mxS[tid];
        int dac = dacsS[tid];
        float ld = logitsF[tid * 48 + dac];
        float ce = -(ld - m - logf(ssum));
        ceArr[tid] = alivesS[tid] ? ce : 0.f;
        afArr[tid] = (float)alivesS[tid];
    }
    __syncthreads();
    if (tid == 0) {
        float s = 0.f, a = 0.f;
        for (int t = 0; t < TSTEPS; t++) { s += ceArr[t]; a += afArr[t]; }
        loss_out[b] = s / a;
    }
}

// ---------------------------------------------------------------------------
// Kernel 6: deterministic final reduction over 4096 per-b losses
// ---------------------------------------------------------------------------
__global__ void reduce_loss(const float* __restrict__ loss, float* __restrict__ out) {
    int tid = threadIdx.x;  // 256
    float s = 0.f;
    for (int i = tid; i < BATCH; i += 256) s += loss[i];
    for (int off = 32; off > 0; off >>= 1) s += __shfl_down(s, off, 64);
    __shared__ float wsum[4];
    if ((tid & 63) == 0) wsum[tid >> 6] = s;
    __syncthreads();
    if (tid == 0) out[0] = (wsum[0] + wsum[1] + wsum[2] + wsum[3]) * (1.0f / (float)BATCH);
}

// ---------------------------------------------------------------------------
extern "C" void kernel_launch(void* const* d_in, const int* in_sizes, int n_in,
                              void* d_out, int out_size, void* d_ws, size_t ws_size,
                              hipStream_t stream) {
    const float* fc_input = (const float*)d_in[0];
    const float* camera   = (const float*)d_in[1];
    const int*   fb       = (const int*)d_in[2];
    const int*   lr       = (const int*)d_in[3];
    const int*   jp       = (const int*)d_in[4];
    const int*   ss       = (const int*)d_in[5];
    const int*   at       = (const int*)d_in[6];
    const float* W1       = (const float*)d_in[7];
    const float* b1       = (const float*)d_in[8];
    const float* W2       = (const float*)d_in[9];
    const float* b2       = (const float*)d_in[10];
    float* out = (float*)d_out;

    char* ws = (char*)d_ws;
    unsigned short* Ab   = (unsigned short*)(ws);                       //  8,388,608 B
    unsigned short* Wt   = (unsigned short*)(ws + 8388608);             //  4,194,304 B
    float*          baseB= (float*)(ws + 12582912);                     // 33,554,432 B
    StepMeta*       meta = (StepMeta*)(ws + 46137344);                  //  2,621,440 B
    float*          lossB= (float*)(ws + 48758784);                     //     16,384 B
    unsigned short* W2T  = (unsigned short*)(ws + 48775168);            //    196,608 B

    scan_kernel<<<BATCH / 256, 256, 0, stream>>>(camera, fb, lr, jp, ss, at, meta);
    prep_kernel<<<4096 + 2048 + 8, 256, 0, stream>>>(fc_input, Ab, W1, Wt, W2, W2T);
    gemm_base<<<dim3(HID / 128, BATCH / 128), 256, 0, stream>>>(Ab, Wt, W1, b1, baseB);
    fused_mlp<<<BATCH, 256, 0, stream>>>(baseB, W1, W2T, b2, meta, lossB);
    reduce_loss<<<1, 256, 0, stream>>>(lossB, out);
}